// Round 1
// baseline (7103.690 us; speedup 1.0000x reference)
//
#include <hip/hip_runtime.h>
#include <math.h>

// CLIP transformer layer: B=8 S=1024 D=1024 H=16 DH=64 FF=4096, fp32 I/O,
// bf16 MFMA internals (threshold = 2% of absmax ~ 0.13, bf16-safe).

typedef __bf16 bf16_t;
typedef __bf16 bf16x4 __attribute__((ext_vector_type(4)));
typedef __bf16 bf16x8 __attribute__((ext_vector_type(8)));
typedef float f32x4 __attribute__((ext_vector_type(4)));

// ---------------------------------------------------------------- helpers
__device__ __forceinline__ void async16(const void* g, void* l) {
    // global -> LDS direct DMA, 16B/lane. LDS dest is wave-uniform base + lane*16.
    __builtin_amdgcn_global_load_lds(
        (const __attribute__((address_space(1))) void*)g,
        (__attribute__((address_space(3))) void*)l,
        16, 0, 0);
}

// ---------------------------------------------------------------- fp32 -> bf16 convert (weights)
__global__ __launch_bounds__(256) void f2b4(const float* __restrict__ in,
                                            bf16_t* __restrict__ out) {
    const int i = (blockIdx.x * 256 + threadIdx.x) * 4;
    const float4 v = *(const float4*)(in + i);
    bf16x4 o;
    o[0] = (bf16_t)v.x; o[1] = (bf16_t)v.y; o[2] = (bf16_t)v.z; o[3] = (bf16_t)v.w;
    *(bf16x4*)(out + i) = o;
}

// ---------------------------------------------------------------- LayerNorm (row of 1024) -> bf16
__global__ __launch_bounds__(256) void ln_bf16(const float* __restrict__ x,
                                               const float* __restrict__ g,
                                               const float* __restrict__ bb,
                                               bf16_t* __restrict__ out) {
    const int tid = threadIdx.x;
    const int row = blockIdx.x;
    const float4 xv = *(const float4*)(x + row * 1024 + tid * 4);
    float s1 = xv.x + xv.y + xv.z + xv.w;
    float s2 = xv.x * xv.x + xv.y * xv.y + xv.z * xv.z + xv.w * xv.w;
#pragma unroll
    for (int m = 32; m >= 1; m >>= 1) {
        s1 += __shfl_xor(s1, m);
        s2 += __shfl_xor(s2, m);
    }
    __shared__ float r1[4], r2[4];
    const int wid = tid >> 6, lane = tid & 63;
    if (lane == 0) { r1[wid] = s1; r2[wid] = s2; }
    __syncthreads();
    s1 = r1[0] + r1[1] + r1[2] + r1[3];
    s2 = r2[0] + r2[1] + r2[2] + r2[3];
    const float mu = s1 * (1.0f / 1024.0f);
    const float var = s2 * (1.0f / 1024.0f) - mu * mu;
    const float rs = rsqrtf(var + 1e-5f);
    const float4 gv = *(const float4*)(g + tid * 4);
    const float4 bv = *(const float4*)(bb + tid * 4);
    bf16x4 o;
    o[0] = (bf16_t)((xv.x - mu) * rs * gv.x + bv.x);
    o[1] = (bf16_t)((xv.y - mu) * rs * gv.y + bv.y);
    o[2] = (bf16_t)((xv.z - mu) * rs * gv.z + bv.z);
    o[3] = (bf16_t)((xv.w - mu) * rs * gv.w + bv.w);
    *(bf16x4*)(out + row * 1024 + tid * 4) = o;
}

// ---------------------------------------------------------------- GEMM: C[M,N] = A[M,K] @ W[N,K]^T + bias
// m97 structure: 128x128 tile, BK=32, 4 waves x (4x4) 16x16x32 MFMA, global_load_lds(16B).
// MODE 0: bias -> bf16 out; MODE 1: bias+gelu -> bf16 out; MODE 2: bias+residual -> fp32 out.
template <int MODE>
__global__ __launch_bounds__(256, 2) void gemm_bt(
    const bf16_t* __restrict__ A, const bf16_t* __restrict__ W,
    const float* __restrict__ bias, const float* __restrict__ resid,
    bf16_t* __restrict__ outb, float* __restrict__ outf, int N, int K) {
    __shared__ bf16_t As[128][32];
    __shared__ bf16_t Bs[128][32];
    const int tid = threadIdx.x;
    const int wid = tid >> 6;
    const int lane = tid & 63;
    const int m0 = blockIdx.y * 128;
    const int n0 = blockIdx.x * 128;
    const int wm = (wid & 1) * 64;   // wave's 64x64 sub-tile
    const int wn = (wid >> 1) * 64;

    // staging: chunk c = j*256 + wid*64 + lane; row=c>>2, kseg=(c&3)*8
    const int c0 = wid * 64 + lane;
    const int r0 = c0 >> 2, s0 = (c0 & 3) * 8;
    const int c1 = 256 + c0;
    const int r1 = c1 >> 2, s1 = (c1 & 3) * 8;

    const bf16_t* pA0 = A + (m0 + r0) * K + s0;
    const bf16_t* pA1 = A + (m0 + r1) * K + s1;
    const bf16_t* pB0 = W + (n0 + r0) * K + s0;
    const bf16_t* pB1 = W + (n0 + r1) * K + s1;
    bf16_t* lA0 = &As[0][0] + wid * 512;          // wave-uniform LDS bases
    bf16_t* lA1 = &As[0][0] + 2048 + wid * 512;
    bf16_t* lB0 = &Bs[0][0] + wid * 512;
    bf16_t* lB1 = &Bs[0][0] + 2048 + wid * 512;

    f32x4 acc[4][4] = {};

    const int kk = (lane >> 4) * 8;  // k-quad within fragment
    const int ra = lane & 15;        // row/col within 16

    for (int k0 = 0; k0 < K; k0 += 32) {
        async16(pA0, lA0);
        async16(pA1, lA1);
        async16(pB0, lB0);
        async16(pB1, lB1);
        pA0 += 32; pA1 += 32; pB0 += 32; pB1 += 32;
        __syncthreads();  // drains vmcnt -> LDS tiles visible
        bf16x8 af[4], bfr[4];
#pragma unroll
        for (int i = 0; i < 4; i++)
            af[i] = *(const bf16x8*)(&As[wm + i * 16 + ra][kk]);
#pragma unroll
        for (int j = 0; j < 4; j++)
            bfr[j] = *(const bf16x8*)(&Bs[wn + j * 16 + ra][kk]);
#pragma unroll
        for (int i = 0; i < 4; i++)
#pragma unroll
            for (int j = 0; j < 4; j++)
                acc[i][j] = __builtin_amdgcn_mfma_f32_16x16x32_bf16(
                    af[i], bfr[j], acc[i][j], 0, 0, 0);
        __syncthreads();  // protect LDS from next iteration's staging
    }

    // epilogue: C/D layout col=lane&15, row=(lane>>4)*4+reg
    const int er = (lane >> 4) * 4;
    const int ec = lane & 15;
#pragma unroll
    for (int i = 0; i < 4; i++) {
#pragma unroll
        for (int j = 0; j < 4; j++) {
#pragma unroll
            for (int r = 0; r < 4; r++) {
                const int row = m0 + wm + i * 16 + er + r;
                const int col = n0 + wn + j * 16 + ec;
                float v = acc[i][j][r] + bias[col];
                if (MODE == 1) {  // tanh-GELU
                    const float u = 0.7978845608028654f * (v + 0.044715f * v * v * v);
                    v = 0.5f * v * (1.0f + tanhf(u));
                }
                const int idx = row * N + col;
                if (MODE == 2) {
                    outf[idx] = v + resid[idx];
                } else {
                    outb[idx] = (bf16_t)v;
                }
            }
        }
    }
}

// ---------------------------------------------------------------- causal flash attention (vector, round-0)
// qkv bf16 [8192][3072] rows=(b*1024+s), cols: q=h*64+d, k=1024+h*64+d, v=2048+h*64+d.
// One wave per 4 query rows; lane owns head-dim d (DH=64=wave width).
__global__ __launch_bounds__(256) void attn_flash(const bf16_t* __restrict__ qkv,
                                                  bf16_t* __restrict__ o) {
    const int wid = threadIdx.x >> 6;
    const int lane = threadIdx.x & 63;
    const int bh = blockIdx.y;
    const int b = bh >> 4;
    const int h = bh & 15;
    const int q0 = blockIdx.x * 16 + wid * 4;
    const int base = (b * 1024) * 3072 + h * 64 + lane;

    float qv[4], m[4], l[4], acc[4];
#pragma unroll
    for (int r = 0; r < 4; r++) {
        qv[r] = (float)qkv[base + (q0 + r) * 3072] * 0.125f;  // 1/sqrt(64)
        m[r] = -3.0e38f;
        l[r] = 0.0f;
        acc[r] = 0.0f;
    }
    const int kmax = q0 + 3;
    for (int k = 0; k <= kmax; k++) {
        const float kv = (float)qkv[base + 1024 + k * 3072];
        const float vv = (float)qkv[base + 2048 + k * 3072];
#pragma unroll
        for (int r = 0; r < 4; r++) {
            float s = qv[r] * kv;
#pragma unroll
            for (int mk = 32; mk >= 1; mk >>= 1) s += __shfl_xor(s, mk);
            if (k <= q0 + r) {  // wave-uniform causal mask
                const float mn = fmaxf(m[r], s);
                const float sc = __expf(m[r] - mn);
                const float p = __expf(s - mn);
                m[r] = mn;
                l[r] = l[r] * sc + p;
                acc[r] = acc[r] * sc + p * vv;
            }
        }
    }
#pragma unroll
    for (int r = 0; r < 4; r++)
        o[(b * 1024 + q0 + r) * 1024 + h * 64 + lane] = (bf16_t)(acc[r] / l[r]);
}

// ---------------------------------------------------------------- launch
extern "C" void kernel_launch(void* const* d_in, const int* in_sizes, int n_in,
                              void* d_out, int out_size, void* d_ws, size_t ws_size,
                              hipStream_t stream) {
    const float* x     = (const float*)d_in[0];
    const float* ln1g  = (const float*)d_in[1];
    const float* ln1b  = (const float*)d_in[2];
    const float* w_qkv = (const float*)d_in[3];
    const float* b_qkv = (const float*)d_in[4];
    const float* w_o   = (const float*)d_in[5];
    const float* b_o   = (const float*)d_in[6];
    const float* ln2g  = (const float*)d_in[7];
    const float* ln2b  = (const float*)d_in[8];
    const float* w1    = (const float*)d_in[9];
    const float* b1    = (const float*)d_in[10];
    const float* w2    = (const float*)d_in[11];
    const float* b2    = (const float*)d_in[12];
    float* out = (float*)d_out;

    // workspace layout (200 MB total)
    char* w = (char*)d_ws;
    bf16_t* wbqkv = (bf16_t*)(w + 0);          //  6 MB  [3072,1024] bf16
    bf16_t* wbo   = (bf16_t*)(w + 6291456);    //  2 MB  [1024,1024]
    bf16_t* wb1   = (bf16_t*)(w + 8388608);    //  8 MB  [4096,1024]
    bf16_t* wb2   = (bf16_t*)(w + 16777216);   //  8 MB  [1024,4096]
    bf16_t* h     = (bf16_t*)(w + 25165824);   // 16 MB  [8192,1024] (LN1 out, reused for LN2 out)
    bf16_t* qkv   = (bf16_t*)(w + 41943040);   // 48 MB  [8192,3072]
    bf16_t* ob    = (bf16_t*)(w + 92274688);   // 16 MB  [8192,1024]
    float*  x1    = (float*)(w + 109051904);   // 32 MB  [8192,1024] fp32
    bf16_t* f     = (bf16_t*)(w + 142606336);  // 64 MB  [8192,4096]

    // weight conversion fp32 -> bf16
    f2b4<<<3072, 256, 0, stream>>>(w_qkv, wbqkv);
    f2b4<<<1024, 256, 0, stream>>>(w_o, wbo);
    f2b4<<<4096, 256, 0, stream>>>(w1, wb1);
    f2b4<<<4096, 256, 0, stream>>>(w2, wb2);

    // h = LN1(x)
    ln_bf16<<<8192, 256, 0, stream>>>(x, ln1g, ln1b, h);
    // qkv = h @ w_qkv^T + b_qkv
    gemm_bt<0><<<dim3(24, 64), 256, 0, stream>>>(h, wbqkv, b_qkv, nullptr, qkv, nullptr, 3072, 1024);
    // ob = causal_attn(qkv)
    attn_flash<<<dim3(64, 128), 256, 0, stream>>>(qkv, ob);
    // x1 = x + ob @ w_o^T + b_o
    gemm_bt<2><<<dim3(8, 64), 256, 0, stream>>>(ob, wbo, b_o, x, nullptr, x1, 1024, 1024);
    // h = LN2(x1)
    ln_bf16<<<8192, 256, 0, stream>>>(x1, ln2g, ln2b, h);
    // f = gelu(h @ w1^T + b1)
    gemm_bt<1><<<dim3(32, 64), 256, 0, stream>>>(h, wb1, b1, nullptr, f, nullptr, 4096, 1024);
    // out = x1 + f @ w2^T + b2
    gemm_bt<2><<<dim3(8, 64), 256, 0, stream>>>(f, wb2, b2, x1, nullptr, out, 1024, 4096);
}

// Round 2
// 528.831 us; speedup vs baseline: 13.4328x; 13.4328x over previous
//
#include <hip/hip_runtime.h>
#include <math.h>

// CLIP transformer layer: B=8 S=1024 D=1024 H=16 DH=64 FF=4096, fp32 I/O,
// bf16 MFMA internals. Round 1: MFMA flash attention (S^T/O^T orientation).

typedef __bf16 bf16_t;
typedef __bf16 bf16x4 __attribute__((ext_vector_type(4)));
typedef __bf16 bf16x8 __attribute__((ext_vector_type(8)));
typedef float f32x4 __attribute__((ext_vector_type(4)));

// ---------------------------------------------------------------- helpers
__device__ __forceinline__ void async16(const void* g, void* l) {
    // global -> LDS direct DMA, 16B/lane. LDS dest is wave-uniform base + lane*16.
    __builtin_amdgcn_global_load_lds(
        (const __attribute__((address_space(1))) void*)g,
        (__attribute__((address_space(3))) void*)l,
        16, 0, 0);
}

// ---------------------------------------------------------------- fp32 -> bf16 convert (weights)
__global__ __launch_bounds__(256) void f2b4(const float* __restrict__ in,
                                            bf16_t* __restrict__ out) {
    const int i = (blockIdx.x * 256 + threadIdx.x) * 4;
    const float4 v = *(const float4*)(in + i);
    bf16x4 o;
    o[0] = (bf16_t)v.x; o[1] = (bf16_t)v.y; o[2] = (bf16_t)v.z; o[3] = (bf16_t)v.w;
    *(bf16x4*)(out + i) = o;
}

// ---------------------------------------------------------------- LayerNorm (row of 1024) -> bf16
__global__ __launch_bounds__(256) void ln_bf16(const float* __restrict__ x,
                                               const float* __restrict__ g,
                                               const float* __restrict__ bb,
                                               bf16_t* __restrict__ out) {
    const int tid = threadIdx.x;
    const int row = blockIdx.x;
    const float4 xv = *(const float4*)(x + row * 1024 + tid * 4);
    float s1 = xv.x + xv.y + xv.z + xv.w;
    float s2 = xv.x * xv.x + xv.y * xv.y + xv.z * xv.z + xv.w * xv.w;
#pragma unroll
    for (int m = 32; m >= 1; m >>= 1) {
        s1 += __shfl_xor(s1, m);
        s2 += __shfl_xor(s2, m);
    }
    __shared__ float r1[4], r2[4];
    const int wid = tid >> 6, lane = tid & 63;
    if (lane == 0) { r1[wid] = s1; r2[wid] = s2; }
    __syncthreads();
    s1 = r1[0] + r1[1] + r1[2] + r1[3];
    s2 = r2[0] + r2[1] + r2[2] + r2[3];
    const float mu = s1 * (1.0f / 1024.0f);
    const float var = s2 * (1.0f / 1024.0f) - mu * mu;
    const float rs = rsqrtf(var + 1e-5f);
    const float4 gv = *(const float4*)(g + tid * 4);
    const float4 bv = *(const float4*)(bb + tid * 4);
    bf16x4 o;
    o[0] = (bf16_t)((xv.x - mu) * rs * gv.x + bv.x);
    o[1] = (bf16_t)((xv.y - mu) * rs * gv.y + bv.y);
    o[2] = (bf16_t)((xv.z - mu) * rs * gv.z + bv.z);
    o[3] = (bf16_t)((xv.w - mu) * rs * gv.w + bv.w);
    *(bf16x4*)(out + row * 1024 + tid * 4) = o;
}

// ---------------------------------------------------------------- GEMM: C[M,N] = A[M,K] @ W[N,K]^T + bias
// MODE 0: bias -> bf16; MODE 1: bias+gelu -> bf16; MODE 2: bias+residual -> fp32.
template <int MODE>
__global__ __launch_bounds__(256, 2) void gemm_bt(
    const bf16_t* __restrict__ A, const bf16_t* __restrict__ W,
    const float* __restrict__ bias, const float* __restrict__ resid,
    bf16_t* __restrict__ outb, float* __restrict__ outf, int N, int K) {
    __shared__ bf16_t As[128][32];
    __shared__ bf16_t Bs[128][32];
    const int tid = threadIdx.x;
    const int wid = tid >> 6;
    const int lane = tid & 63;
    const int m0 = blockIdx.y * 128;
    const int n0 = blockIdx.x * 128;
    const int wm = (wid & 1) * 64;
    const int wn = (wid >> 1) * 64;

    const int c0 = wid * 64 + lane;
    const int r0 = c0 >> 2, s0 = (c0 & 3) * 8;
    const int c1 = 256 + c0;
    const int r1 = c1 >> 2, s1 = (c1 & 3) * 8;

    const bf16_t* pA0 = A + (m0 + r0) * K + s0;
    const bf16_t* pA1 = A + (m0 + r1) * K + s1;
    const bf16_t* pB0 = W + (n0 + r0) * K + s0;
    const bf16_t* pB1 = W + (n0 + r1) * K + s1;
    bf16_t* lA0 = &As[0][0] + wid * 512;
    bf16_t* lA1 = &As[0][0] + 2048 + wid * 512;
    bf16_t* lB0 = &Bs[0][0] + wid * 512;
    bf16_t* lB1 = &Bs[0][0] + 2048 + wid * 512;

    f32x4 acc[4][4] = {};

    const int kk = (lane >> 4) * 8;
    const int ra = lane & 15;

    for (int k0 = 0; k0 < K; k0 += 32) {
        async16(pA0, lA0);
        async16(pA1, lA1);
        async16(pB0, lB0);
        async16(pB1, lB1);
        pA0 += 32; pA1 += 32; pB0 += 32; pB1 += 32;
        __syncthreads();
        bf16x8 af[4], bfr[4];
#pragma unroll
        for (int i = 0; i < 4; i++)
            af[i] = *(const bf16x8*)(&As[wm + i * 16 + ra][kk]);
#pragma unroll
        for (int j = 0; j < 4; j++)
            bfr[j] = *(const bf16x8*)(&Bs[wn + j * 16 + ra][kk]);
#pragma unroll
        for (int i = 0; i < 4; i++)
#pragma unroll
            for (int j = 0; j < 4; j++)
                acc[i][j] = __builtin_amdgcn_mfma_f32_16x16x32_bf16(
                    af[i], bfr[j], acc[i][j], 0, 0, 0);
        __syncthreads();
    }

    const int er = (lane >> 4) * 4;
    const int ec = lane & 15;
#pragma unroll
    for (int i = 0; i < 4; i++) {
#pragma unroll
        for (int j = 0; j < 4; j++) {
#pragma unroll
            for (int r = 0; r < 4; r++) {
                const int row = m0 + wm + i * 16 + er + r;
                const int col = n0 + wn + j * 16 + ec;
                float v = acc[i][j][r] + bias[col];
                if (MODE == 1) {
                    const float u = 0.7978845608028654f * (v + 0.044715f * v * v * v);
                    v = 0.5f * v * (1.0f + tanhf(u));
                }
                const int idx = row * N + col;
                if (MODE == 2) {
                    outf[idx] = v + resid[idx];
                } else {
                    outb[idx] = (bf16_t)v;
                }
            }
        }
    }
}

// ---------------------------------------------------------------- V transpose: qkv V-part -> Vt[b*16+h][d=64][s=1024]
// Wave handles one s-octet: 8 coalesced 128B row-loads, 1 b128 store per lane.
__global__ __launch_bounds__(256) void vtrans(const bf16_t* __restrict__ qkv,
                                              bf16_t* __restrict__ vt) {
    const int wid = threadIdx.x >> 6;
    const int lane = threadIdx.x & 63;
    const int bh = blockIdx.y;
    const int b = bh >> 4, h = bh & 15;
    const int so = blockIdx.x * 4 + wid;  // s-octet 0..127
    const bf16_t* src = qkv + (size_t)(b * 1024 + so * 8) * 3072 + 2048 + h * 64 + lane;
    bf16x8 v;
#pragma unroll
    for (int i = 0; i < 8; i++) v[i] = src[i * 3072];
    *(bf16x8*)(vt + ((size_t)bh * 64 + lane) * 1024 + so * 8) = v;
}

// ---------------------------------------------------------------- MFMA causal flash attention
// Grid (16 q-blocks, 128 bh), 256 thr = 4 waves; wave owns 16 queries.
// S^T = K @ Q^T (C: row=key, col=q=lane&15); O^T = V^T @ P^T (C: row=d, col=q).
// K/Vt tiles staged via async16 with XOR-swizzled GLOBAL source so LDS frag
// reads (b128, key/d-contiguous) are bank-conflict-free without padding.
__global__ __launch_bounds__(256) void attn_mfma(const bf16_t* __restrict__ qkv,
                                                 const bf16_t* __restrict__ vt,
                                                 bf16_t* __restrict__ o) {
    __shared__ bf16_t Ks[4096];       // [key=64][dseg swizzled]
    __shared__ bf16_t Vs[4096];       // [d=64][kseg swizzled]
    __shared__ bf16_t Ps[4][16][72];  // per-wave P[q][key], padded stride 72 (144B, 16B-mult)
    const int tid = threadIdx.x;
    const int w = tid >> 6;
    const int lane = tid & 63;
    const int l15 = lane & 15;
    const int quad = lane >> 4;
    const int qb = blockIdx.x;   // q-block of 64
    const int bh = blockIdx.y;
    const int b = bh >> 4, h = bh & 15;

    const int qrow = b * 1024 + qb * 64 + w * 16;  // wave's first query row (global)
    const int qmaxw = qb * 64 + w * 16 + 15;       // wave's max query (in-seq)

    // Q^T B-frags: lane holds Q[q=l15][d=f*32+quad*8+j], scaled by 1/8 (exact pow2)
    bf16x8 qf[2];
#pragma unroll
    for (int f = 0; f < 2; f++) {
        bf16x8 t = *(const bf16x8*)(qkv + (size_t)(qrow + l15) * 3072 + h * 64 + f * 32 + quad * 8);
#pragma unroll
        for (int e = 0; e < 8; e++) t[e] = (bf16_t)((float)t[e] * 0.125f);
        qf[f] = t;
    }

    f32x4 Ot[4] = {};  // O^T acc: row d=db*16+quad*4+reg, col q=l15
    float mrow = -3.0e38f, lrow = 0.0f;

    const int c0 = w * 64 + lane;  // staging chunk ids (8 bf16 each)
    const int c1 = 256 + c0;
    const int r0 = c0 >> 3, g0 = (((c0 & 7) ^ (r0 & 7))) * 8;  // swizzled source seg
    const int r1 = c1 >> 3, g1 = (((c1 & 7) ^ (r1 & 7))) * 8;

    const bf16_t* kbase = qkv + (size_t)(b * 1024) * 3072 + 1024 + h * 64;
    const bf16_t* vbase = vt + (size_t)bh * 64 * 1024;

    for (int kt = 0; kt <= qb; kt++) {
        // stage K[key][d] and Vt[d][key] tiles (XOR-swizzled global source)
        async16(kbase + (size_t)(kt * 64 + r0) * 3072 + g0, Ks + w * 512);
        async16(kbase + (size_t)(kt * 64 + r1) * 3072 + g1, Ks + 2048 + w * 512);
        async16(vbase + (size_t)r0 * 1024 + kt * 64 + g0, Vs + w * 512);
        async16(vbase + (size_t)r1 * 1024 + kt * 64 + g1, Vs + 2048 + w * 512);
        __syncthreads();

        // S^T = K @ Q^T : 4 key-blocks x (2 mfma over d)
        f32x4 sf[4];
#pragma unroll
        for (int kb = 0; kb < 4; kb++) {
            if (kt * 64 + kb * 16 > qmaxw) {  // fully masked key-block (wave-uniform)
                sf[kb] = (f32x4){-3.0e38f, -3.0e38f, -3.0e38f, -3.0e38f};
                continue;
            }
            const int r = kb * 16 + l15;  // key row in tile
            f32x4 acc = {};
#pragma unroll
            for (int f = 0; f < 2; f++) {
                const int seg = (f * 4 + quad) ^ (r & 7);
                const bf16x8 kf = *(const bf16x8*)(Ks + r * 64 + seg * 8);
                acc = __builtin_amdgcn_mfma_f32_16x16x32_bf16(kf, qf[f], acc, 0, 0, 0);
            }
            if (kt == qb && kb == w) {  // diagonal 16-block: per-element causal mask
#pragma unroll
                for (int rr = 0; rr < 4; rr++)
                    if (quad * 4 + rr > l15) acc[rr] = -3.0e38f;
            }
            sf[kb] = acc;
        }

        // online softmax over columns (q = l15): in-lane 16 + shuffle over quads
        float tmax = -3.0e38f;
#pragma unroll
        for (int kb = 0; kb < 4; kb++)
#pragma unroll
            for (int rr = 0; rr < 4; rr++) tmax = fmaxf(tmax, sf[kb][rr]);
        tmax = fmaxf(tmax, __shfl_xor(tmax, 16));
        tmax = fmaxf(tmax, __shfl_xor(tmax, 32));
        const float mnew = fmaxf(mrow, tmax);
        const float alpha = __expf(mrow - mnew);
        float psum = 0.0f;
#pragma unroll
        for (int kb = 0; kb < 4; kb++) {
            bf16x4 pk;
#pragma unroll
            for (int rr = 0; rr < 4; rr++) {
                const float p = __expf(sf[kb][rr] - mnew);
                psum += p;
                pk[rr] = (bf16_t)p;
            }
            // P^T regs are 4 consecutive keys -> vector write to Ps[q][key]
            *(bf16x4*)(&Ps[w][l15][kb * 16 + quad * 4]) = pk;
        }
        psum += __shfl_xor(psum, 16);
        psum += __shfl_xor(psum, 32);
        lrow = lrow * alpha + psum;
        mrow = mnew;
#pragma unroll
        for (int db = 0; db < 4; db++)
#pragma unroll
            for (int rr = 0; rr < 4; rr++) Ot[db][rr] *= alpha;

        // O^T += V^T @ P^T : 2 k-steps x 4 d-blocks
#pragma unroll
        for (int ks = 0; ks < 2; ks++) {
            if (kt * 64 + ks * 32 > qmaxw) break;  // all-zero P (wave-uniform)
            const bf16x8 pf = *(const bf16x8*)(&Ps[w][l15][ks * 32 + quad * 8]);
#pragma unroll
            for (int db = 0; db < 4; db++) {
                const int d = db * 16 + l15;
                const int seg = (ks * 4 + quad) ^ (d & 7);
                const bf16x8 vf = *(const bf16x8*)(Vs + d * 64 + seg * 8);
                Ot[db] = __builtin_amdgcn_mfma_f32_16x16x32_bf16(vf, pf, Ot[db], 0, 0, 0);
            }
        }
        __syncthreads();  // protect Ks/Vs before next staging
    }

    // epilogue: O = O^T / l ; lane holds 4 consecutive d per db at q=l15
    const float rl = 1.0f / lrow;
#pragma unroll
    for (int db = 0; db < 4; db++) {
        bf16x4 ov;
#pragma unroll
        for (int rr = 0; rr < 4; rr++) ov[rr] = (bf16_t)(Ot[db][rr] * rl);
        *(bf16x4*)(o + (size_t)(qrow + l15) * 1024 + h * 64 + db * 16 + quad * 4) = ov;
    }
}

// ---------------------------------------------------------------- launch
extern "C" void kernel_launch(void* const* d_in, const int* in_sizes, int n_in,
                              void* d_out, int out_size, void* d_ws, size_t ws_size,
                              hipStream_t stream) {
    const float* x     = (const float*)d_in[0];
    const float* ln1g  = (const float*)d_in[1];
    const float* ln1b  = (const float*)d_in[2];
    const float* w_qkv = (const float*)d_in[3];
    const float* b_qkv = (const float*)d_in[4];
    const float* w_o   = (const float*)d_in[5];
    const float* b_o   = (const float*)d_in[6];
    const float* ln2g  = (const float*)d_in[7];
    const float* ln2b  = (const float*)d_in[8];
    const float* w1    = (const float*)d_in[9];
    const float* b1    = (const float*)d_in[10];
    const float* w2    = (const float*)d_in[11];
    const float* b2    = (const float*)d_in[12];
    float* out = (float*)d_out;

    // workspace layout (200 MB total)
    char* w = (char*)d_ws;
    bf16_t* wbqkv = (bf16_t*)(w + 0);          //  6 MB  [3072,1024] bf16
    bf16_t* wbo   = (bf16_t*)(w + 6291456);    //  2 MB  [1024,1024]
    bf16_t* wb1   = (bf16_t*)(w + 8388608);    //  8 MB  [4096,1024]
    bf16_t* wb2   = (bf16_t*)(w + 16777216);   //  8 MB  [1024,4096]
    bf16_t* h     = (bf16_t*)(w + 25165824);   // 16 MB  [8192,1024] (LN1/LN2 out)
    bf16_t* qkv   = (bf16_t*)(w + 41943040);   // 48 MB  [8192,3072]
    bf16_t* ob    = (bf16_t*)(w + 92274688);   // 16 MB  [8192,1024]
    float*  x1    = (float*)(w + 109051904);   // 32 MB  [8192,1024] fp32
    bf16_t* f     = (bf16_t*)(w + 142606336);  // 64 MB  [8192,4096] (FFN1 out)
    // Vt aliases f's region: attention finishes before FFN1 writes f.
    bf16_t* vtb   = (bf16_t*)(w + 142606336);  // 16 MB  [128][64][1024]

    f2b4<<<3072, 256, 0, stream>>>(w_qkv, wbqkv);
    f2b4<<<1024, 256, 0, stream>>>(w_o, wbo);
    f2b4<<<4096, 256, 0, stream>>>(w1, wb1);
    f2b4<<<4096, 256, 0, stream>>>(w2, wb2);

    ln_bf16<<<8192, 256, 0, stream>>>(x, ln1g, ln1b, h);
    gemm_bt<0><<<dim3(24, 64), 256, 0, stream>>>(h, wbqkv, b_qkv, nullptr, qkv, nullptr, 3072, 1024);
    vtrans<<<dim3(32, 128), 256, 0, stream>>>(qkv, vtb);
    attn_mfma<<<dim3(16, 128), 256, 0, stream>>>(qkv, vtb, ob);
    gemm_bt<2><<<dim3(8, 64), 256, 0, stream>>>(ob, wbo, b_o, x, nullptr, x1, 1024, 1024);
    ln_bf16<<<8192, 256, 0, stream>>>(x1, ln2g, ln2b, h);
    gemm_bt<1><<<dim3(32, 64), 256, 0, stream>>>(h, wb1, b1, nullptr, f, nullptr, 4096, 1024);
    gemm_bt<2><<<dim3(8, 64), 256, 0, stream>>>(f, wb2, b2, x1, nullptr, out, 1024, 4096);
}

// Round 3
// 503.567 us; speedup vs baseline: 14.1067x; 1.0502x over previous
//
#include <hip/hip_runtime.h>
#include <math.h>

// CLIP transformer layer: B=8 S=1024 D=1024 H=16 DH=64 FF=4096, fp32 I/O,
// bf16 MFMA internals. Round 2: BK=64 XOR-swizzled conflict-free GEMM + L2 block swizzle.

typedef __bf16 bf16_t;
typedef __bf16 bf16x4 __attribute__((ext_vector_type(4)));
typedef __bf16 bf16x8 __attribute__((ext_vector_type(8)));
typedef float f32x4 __attribute__((ext_vector_type(4)));

// ---------------------------------------------------------------- helpers
__device__ __forceinline__ void async16(const void* g, void* l) {
    // global -> LDS direct DMA, 16B/lane. LDS dest is wave-uniform base + lane*16.
    __builtin_amdgcn_global_load_lds(
        (const __attribute__((address_space(1))) void*)g,
        (__attribute__((address_space(3))) void*)l,
        16, 0, 0);
}

// ---------------------------------------------------------------- fp32 -> bf16 convert (weights)
__global__ __launch_bounds__(256) void f2b4(const float* __restrict__ in,
                                            bf16_t* __restrict__ out) {
    const int i = (blockIdx.x * 256 + threadIdx.x) * 4;
    const float4 v = *(const float4*)(in + i);
    bf16x4 o;
    o[0] = (bf16_t)v.x; o[1] = (bf16_t)v.y; o[2] = (bf16_t)v.z; o[3] = (bf16_t)v.w;
    *(bf16x4*)(out + i) = o;
}

// ---------------------------------------------------------------- LayerNorm (row of 1024) -> bf16
__global__ __launch_bounds__(256) void ln_bf16(const float* __restrict__ x,
                                               const float* __restrict__ g,
                                               const float* __restrict__ bb,
                                               bf16_t* __restrict__ out) {
    const int tid = threadIdx.x;
    const int row = blockIdx.x;
    const float4 xv = *(const float4*)(x + row * 1024 + tid * 4);
    float s1 = xv.x + xv.y + xv.z + xv.w;
    float s2 = xv.x * xv.x + xv.y * xv.y + xv.z * xv.z + xv.w * xv.w;
#pragma unroll
    for (int m = 32; m >= 1; m >>= 1) {
        s1 += __shfl_xor(s1, m);
        s2 += __shfl_xor(s2, m);
    }
    __shared__ float r1[4], r2[4];
    const int wid = tid >> 6, lane = tid & 63;
    if (lane == 0) { r1[wid] = s1; r2[wid] = s2; }
    __syncthreads();
    s1 = r1[0] + r1[1] + r1[2] + r1[3];
    s2 = r2[0] + r2[1] + r2[2] + r2[3];
    const float mu = s1 * (1.0f / 1024.0f);
    const float var = s2 * (1.0f / 1024.0f) - mu * mu;
    const float rs = rsqrtf(var + 1e-5f);
    const float4 gv = *(const float4*)(g + tid * 4);
    const float4 bv = *(const float4*)(bb + tid * 4);
    bf16x4 o;
    o[0] = (bf16_t)((xv.x - mu) * rs * gv.x + bv.x);
    o[1] = (bf16_t)((xv.y - mu) * rs * gv.y + bv.y);
    o[2] = (bf16_t)((xv.z - mu) * rs * gv.z + bv.z);
    o[3] = (bf16_t)((xv.w - mu) * rs * gv.w + bv.w);
    *(bf16x4*)(out + row * 1024 + tid * 4) = o;
}

// ---------------------------------------------------------------- GEMM: C[M,N] = A[M,K] @ W[N,K]^T + bias
// 128x128 tile, BK=64, XOR-swizzled LDS (conflict-free b128 frag reads),
// async16 staging with swizzle applied to the GLOBAL source address.
// 1D grid, group-of-8 m-block swizzle for W-tile L2 reuse.
// MODE 0: bias -> bf16; MODE 1: bias+gelu -> bf16; MODE 2: bias+residual -> fp32.
template <int MODE>
__global__ __launch_bounds__(256, 2) void gemm_bt(
    const bf16_t* __restrict__ A, const bf16_t* __restrict__ W,
    const float* __restrict__ bias, const float* __restrict__ resid,
    bf16_t* __restrict__ outb, float* __restrict__ outf, int N, int K) {
    __shared__ bf16_t As[128 * 64];
    __shared__ bf16_t Bs[128 * 64];
    const int tid = threadIdx.x;
    const int w = tid >> 6;
    const int lane = tid & 63;
    const int l15 = lane & 15;
    const int quad = lane >> 4;

    // block swizzle: consecutive blocks share the n-column (W-tile reuse)
    const int nbn = N >> 7;
    const int per = 8 * nbn;
    const int lid = blockIdx.x;
    const int bm = (lid / per) * 8 + (lid % per) % 8;
    const int bn = (lid % per) / 8;
    const int m0 = bm * 128;
    const int n0 = bn * 128;
    const int wm = (w & 1) * 64;
    const int wn = (w >> 1) * 64;

    // staging: 4 calls/wave per operand; chunk c = q*256 + w*64 + lane (16B each).
    // LDS slot (row r, seg s) holds global k-seg (s ^ (r&7)).
    int rr[4], so[4];
#pragma unroll
    for (int q = 0; q < 4; q++) {
        const int c = q * 256 + w * 64 + lane;
        rr[q] = c >> 3;
        so[q] = ((c & 7) ^ (rr[q] & 7)) * 8;
    }
    const bf16_t* pA[4];
    const bf16_t* pB[4];
#pragma unroll
    for (int q = 0; q < 4; q++) {
        pA[q] = A + (size_t)(m0 + rr[q]) * K + so[q];
        pB[q] = W + (size_t)(n0 + rr[q]) * K + so[q];
    }

    f32x4 acc[4][4] = {};

    for (int k0 = 0; k0 < K; k0 += 64) {
#pragma unroll
        for (int q = 0; q < 4; q++) {
            async16(pA[q], As + q * 2048 + w * 512);
            async16(pB[q], Bs + q * 2048 + w * 512);
            pA[q] += 64; pB[q] += 64;
        }
        __syncthreads();  // drains vmcnt -> LDS tiles visible

        bf16x8 af[4][2], bfr[4][2];
#pragma unroll
        for (int i = 0; i < 4; i++) {
            const int r = wm + i * 16 + l15;
#pragma unroll
            for (int f = 0; f < 2; f++) {
                const int slot = (f * 4 + quad) ^ (r & 7);
                af[i][f] = *(const bf16x8*)(As + r * 64 + slot * 8);
            }
        }
#pragma unroll
        for (int j = 0; j < 4; j++) {
            const int r = wn + j * 16 + l15;
#pragma unroll
            for (int f = 0; f < 2; f++) {
                const int slot = (f * 4 + quad) ^ (r & 7);
                bfr[j][f] = *(const bf16x8*)(Bs + r * 64 + slot * 8);
            }
        }
#pragma unroll
        for (int i = 0; i < 4; i++)
#pragma unroll
            for (int j = 0; j < 4; j++)
#pragma unroll
                for (int f = 0; f < 2; f++)
                    acc[i][j] = __builtin_amdgcn_mfma_f32_16x16x32_bf16(
                        af[i][f], bfr[j][f], acc[i][j], 0, 0, 0);
        __syncthreads();  // protect LDS from next iteration's staging
    }

    // epilogue: C/D layout col=lane&15 (n), row=(lane>>4)*4+reg (m)
    const int er = quad * 4;
#pragma unroll
    for (int i = 0; i < 4; i++) {
#pragma unroll
        for (int j = 0; j < 4; j++) {
#pragma unroll
            for (int r = 0; r < 4; r++) {
                const int row = m0 + wm + i * 16 + er + r;
                const int col = n0 + wn + j * 16 + l15;
                float v = acc[i][j][r] + bias[col];
                if (MODE == 1) {
                    const float u = 0.7978845608028654f * (v + 0.044715f * v * v * v);
                    v = 0.5f * v * (1.0f + tanhf(u));
                }
                const size_t idx = (size_t)row * N + col;
                if (MODE == 2) {
                    outf[idx] = v + resid[idx];
                } else {
                    outb[idx] = (bf16_t)v;
                }
            }
        }
    }
}

// ---------------------------------------------------------------- V transpose: qkv V-part -> Vt[b*16+h][d=64][s=1024]
__global__ __launch_bounds__(256) void vtrans(const bf16_t* __restrict__ qkv,
                                              bf16_t* __restrict__ vt) {
    const int wid = threadIdx.x >> 6;
    const int lane = threadIdx.x & 63;
    const int bh = blockIdx.y;
    const int b = bh >> 4, h = bh & 15;
    const int so = blockIdx.x * 4 + wid;  // s-octet 0..127
    const bf16_t* src = qkv + (size_t)(b * 1024 + so * 8) * 3072 + 2048 + h * 64 + lane;
    bf16x8 v;
#pragma unroll
    for (int i = 0; i < 8; i++) v[i] = src[i * 3072];
    *(bf16x8*)(vt + ((size_t)bh * 64 + lane) * 1024 + so * 8) = v;
}

// ---------------------------------------------------------------- MFMA causal flash attention
// Grid (16 q-blocks, 128 bh), 256 thr = 4 waves; wave owns 16 queries.
// S^T = K @ Q^T (C: row=key, col=q=lane&15); O^T = V^T @ P^T (C: row=d, col=q).
__global__ __launch_bounds__(256) void attn_mfma(const bf16_t* __restrict__ qkv,
                                                 const bf16_t* __restrict__ vt,
                                                 bf16_t* __restrict__ o) {
    __shared__ bf16_t Ks[4096];       // [key=64][dseg swizzled]
    __shared__ bf16_t Vs[4096];       // [d=64][kseg swizzled]
    __shared__ bf16_t Ps[4][16][72];  // per-wave P[q][key], padded stride 72
    const int tid = threadIdx.x;
    const int w = tid >> 6;
    const int lane = tid & 63;
    const int l15 = lane & 15;
    const int quad = lane >> 4;
    const int qb = blockIdx.x;
    const int bh = blockIdx.y;
    const int b = bh >> 4, h = bh & 15;

    const int qrow = b * 1024 + qb * 64 + w * 16;
    const int qmaxw = qb * 64 + w * 16 + 15;

    bf16x8 qf[2];
#pragma unroll
    for (int f = 0; f < 2; f++) {
        bf16x8 t = *(const bf16x8*)(qkv + (size_t)(qrow + l15) * 3072 + h * 64 + f * 32 + quad * 8);
#pragma unroll
        for (int e = 0; e < 8; e++) t[e] = (bf16_t)((float)t[e] * 0.125f);
        qf[f] = t;
    }

    f32x4 Ot[4] = {};
    float mrow = -3.0e38f, lrow = 0.0f;

    const int c0 = w * 64 + lane;
    const int c1 = 256 + c0;
    const int r0 = c0 >> 3, g0 = (((c0 & 7) ^ (r0 & 7))) * 8;
    const int r1 = c1 >> 3, g1 = (((c1 & 7) ^ (r1 & 7))) * 8;

    const bf16_t* kbase = qkv + (size_t)(b * 1024) * 3072 + 1024 + h * 64;
    const bf16_t* vbase = vt + (size_t)bh * 64 * 1024;

    for (int kt = 0; kt <= qb; kt++) {
        async16(kbase + (size_t)(kt * 64 + r0) * 3072 + g0, Ks + w * 512);
        async16(kbase + (size_t)(kt * 64 + r1) * 3072 + g1, Ks + 2048 + w * 512);
        async16(vbase + (size_t)r0 * 1024 + kt * 64 + g0, Vs + w * 512);
        async16(vbase + (size_t)r1 * 1024 + kt * 64 + g1, Vs + 2048 + w * 512);
        __syncthreads();

        f32x4 sf[4];
#pragma unroll
        for (int kb = 0; kb < 4; kb++) {
            if (kt * 64 + kb * 16 > qmaxw) {
                sf[kb] = (f32x4){-3.0e38f, -3.0e38f, -3.0e38f, -3.0e38f};
                continue;
            }
            const int r = kb * 16 + l15;
            f32x4 acc = {};
#pragma unroll
            for (int f = 0; f < 2; f++) {
                const int seg = (f * 4 + quad) ^ (r & 7);
                const bf16x8 kf = *(const bf16x8*)(Ks + r * 64 + seg * 8);
                acc = __builtin_amdgcn_mfma_f32_16x16x32_bf16(kf, qf[f], acc, 0, 0, 0);
            }
            if (kt == qb && kb == w) {
#pragma unroll
                for (int rr2 = 0; rr2 < 4; rr2++)
                    if (quad * 4 + rr2 > l15) acc[rr2] = -3.0e38f;
            }
            sf[kb] = acc;
        }

        float tmax = -3.0e38f;
#pragma unroll
        for (int kb = 0; kb < 4; kb++)
#pragma unroll
            for (int rr2 = 0; rr2 < 4; rr2++) tmax = fmaxf(tmax, sf[kb][rr2]);
        tmax = fmaxf(tmax, __shfl_xor(tmax, 16));
        tmax = fmaxf(tmax, __shfl_xor(tmax, 32));
        const float mnew = fmaxf(mrow, tmax);
        const float alpha = __expf(mrow - mnew);
        float psum = 0.0f;
#pragma unroll
        for (int kb = 0; kb < 4; kb++) {
            bf16x4 pk;
#pragma unroll
            for (int rr2 = 0; rr2 < 4; rr2++) {
                const float p = __expf(sf[kb][rr2] - mnew);
                psum += p;
                pk[rr2] = (bf16_t)p;
            }
            *(bf16x4*)(&Ps[w][l15][kb * 16 + quad * 4]) = pk;
        }
        psum += __shfl_xor(psum, 16);
        psum += __shfl_xor(psum, 32);
        lrow = lrow * alpha + psum;
        mrow = mnew;
#pragma unroll
        for (int db = 0; db < 4; db++)
#pragma unroll
            for (int rr2 = 0; rr2 < 4; rr2++) Ot[db][rr2] *= alpha;

#pragma unroll
        for (int ks = 0; ks < 2; ks++) {
            if (kt * 64 + ks * 32 > qmaxw) break;
            const bf16x8 pf = *(const bf16x8*)(&Ps[w][l15][ks * 32 + quad * 8]);
#pragma unroll
            for (int db = 0; db < 4; db++) {
                const int d = db * 16 + l15;
                const int seg = (ks * 4 + quad) ^ (d & 7);
                const bf16x8 vf = *(const bf16x8*)(Vs + d * 64 + seg * 8);
                Ot[db] = __builtin_amdgcn_mfma_f32_16x16x32_bf16(vf, pf, Ot[db], 0, 0, 0);
            }
        }
        __syncthreads();
    }

    const float rl = 1.0f / lrow;
#pragma unroll
    for (int db = 0; db < 4; db++) {
        bf16x4 ov;
#pragma unroll
        for (int rr2 = 0; rr2 < 4; rr2++) ov[rr2] = (bf16_t)(Ot[db][rr2] * rl);
        *(bf16x4*)(o + (size_t)(qrow + l15) * 1024 + h * 64 + db * 16 + quad * 4) = ov;
    }
}

// ---------------------------------------------------------------- launch
extern "C" void kernel_launch(void* const* d_in, const int* in_sizes, int n_in,
                              void* d_out, int out_size, void* d_ws, size_t ws_size,
                              hipStream_t stream) {
    const float* x     = (const float*)d_in[0];
    const float* ln1g  = (const float*)d_in[1];
    const float* ln1b  = (const float*)d_in[2];
    const float* w_qkv = (const float*)d_in[3];
    const float* b_qkv = (const float*)d_in[4];
    const float* w_o   = (const float*)d_in[5];
    const float* b_o   = (const float*)d_in[6];
    const float* ln2g  = (const float*)d_in[7];
    const float* ln2b  = (const float*)d_in[8];
    const float* w1    = (const float*)d_in[9];
    const float* b1    = (const float*)d_in[10];
    const float* w2    = (const float*)d_in[11];
    const float* b2    = (const float*)d_in[12];
    float* out = (float*)d_out;

    char* w = (char*)d_ws;
    bf16_t* wbqkv = (bf16_t*)(w + 0);          //  6 MB  [3072,1024] bf16
    bf16_t* wbo   = (bf16_t*)(w + 6291456);    //  2 MB  [1024,1024]
    bf16_t* wb1   = (bf16_t*)(w + 8388608);    //  8 MB  [4096,1024]
    bf16_t* wb2   = (bf16_t*)(w + 16777216);   //  8 MB  [1024,4096]
    bf16_t* h     = (bf16_t*)(w + 25165824);   // 16 MB  [8192,1024] (LN1/LN2 out)
    bf16_t* qkv   = (bf16_t*)(w + 41943040);   // 48 MB  [8192,3072]
    bf16_t* ob    = (bf16_t*)(w + 92274688);   // 16 MB  [8192,1024]
    float*  x1    = (float*)(w + 109051904);   // 32 MB  [8192,1024] fp32
    bf16_t* f     = (bf16_t*)(w + 142606336);  // 64 MB  [8192,4096] (FFN1 out)
    bf16_t* vtb   = (bf16_t*)(w + 142606336);  // 16 MB  [128][64][1024] (aliases f; done before FFN1)

    f2b4<<<3072, 256, 0, stream>>>(w_qkv, wbqkv);
    f2b4<<<1024, 256, 0, stream>>>(w_o, wbo);
    f2b4<<<4096, 256, 0, stream>>>(w1, wb1);
    f2b4<<<4096, 256, 0, stream>>>(w2, wb2);

    ln_bf16<<<8192, 256, 0, stream>>>(x, ln1g, ln1b, h);
    gemm_bt<0><<<64 * 24, 256, 0, stream>>>(h, wbqkv, b_qkv, nullptr, qkv, nullptr, 3072, 1024);
    vtrans<<<dim3(32, 128), 256, 0, stream>>>(qkv, vtb);
    attn_mfma<<<dim3(16, 128), 256, 0, stream>>>(qkv, vtb, ob);
    gemm_bt<2><<<64 * 8, 256, 0, stream>>>(ob, wbo, b_o, x, nullptr, x1, 1024, 1024);
    ln_bf16<<<8192, 256, 0, stream>>>(x1, ln2g, ln2b, h);
    gemm_bt<1><<<64 * 32, 256, 0, stream>>>(h, wb1, b1, nullptr, f, nullptr, 4096, 1024);
    gemm_bt<2><<<64 * 8, 256, 0, stream>>>(f, wb2, b2, x1, nullptr, out, 1024, 4096);
}